// Round 4
// baseline (437.326 us; speedup 1.0000x reference)
//
#include <hip/hip_runtime.h>
#include <hip/hip_bf16.h>

typedef unsigned int  uint;
typedef unsigned short ushort;

#define NB   8
#define NC   64
#define LL   32768
#define KK   5
#define NG   4
#define NDG  2
#define NGD  8        // NG*NDG
#define NCD  8        // NC / NGD
#define NOFF 40       // NGD*KK
#define DWK  7

__device__ __forceinline__ float bits2f(uint u) {
  union { uint u; float f; } v; v.u = u; return v.f;
}
__device__ __forceinline__ float bf2f(ushort u) {
  union { uint u; float f; } v; v.u = ((uint)u) << 16; return v.f;
}
__device__ __forceinline__ ushort f2bf(float f) {   // round-to-nearest-even
  union { float f; uint u; } v; v.f = f;
  uint r = (v.u + 0x7fffu + ((v.u >> 16) & 1u)) >> 16;
  return (ushort)r;
}

// ---------------------------------------------------------------------------
// k_prep: permute f32 weights into MAC-friendly layouts.
//  wtA[c*40+o] = pw_off_w[o,c]   wtM[c*40+o] = pw_m_w[o,c]
//  wtW[(((g*2+d)*8+c)*5+k)*16+o] = weight[g*16+o, d*8+c, k]
// ---------------------------------------------------------------------------
__global__ __launch_bounds__(256) void k_prep(
    const float* __restrict__ pwA, const float* __restrict__ pwM,
    const float* __restrict__ mw,
    float* __restrict__ wtA, float* __restrict__ wtM, float* __restrict__ wtW)
{
  int idx = blockIdx.x * 256 + threadIdx.x;
  if (idx < 2560) {
    int c = idx / 40, o = idx % 40;
    wtA[idx] = pwA[o * NC + c];
  } else if (idx < 5120) {
    int j = idx - 2560;
    int c = j / 40, o = j % 40;
    wtM[j] = pwM[o * NC + c];
  } else if (idx < 10240) {
    int j = idx - 5120;
    int o = j & 15; int tt = j >> 4;
    int k = tt % 5;  tt /= 5;
    int c = tt % 8;  tt /= 8;
    int d = tt & 1;  int g = tt >> 1;
    wtW[j] = mw[((g * 16 + o) * 16 + d * 8 + c) * KK + k];
  }
}

// ---------------------------------------------------------------------------
// k_statsx: ONE pass over x produces (a) partial GN stats for both branches
// (per-chunk, deterministic), (b) channel-packed bf16 xT[b][gd][l][8c].
// Grid: blk = (b*8+gd)*8+chunk; block = 8 ch x 4096 l.
// ---------------------------------------------------------------------------
__global__ __launch_bounds__(256) void k_statsx(
    const float* __restrict__ x,
    const float* __restrict__ dwAw, const float* __restrict__ dwAb,
    const float* __restrict__ dwMw, const float* __restrict__ dwMb,
    ushort* __restrict__ xT, float4* __restrict__ partial)
{
  __shared__ float tile[8][256];     // [c_local][l]  8 KB
  __shared__ float4 red[256];        // 4 KB

  int t     = threadIdx.x;
  int blk   = blockIdx.x;
  int chunk = blk & 7;
  int gd    = (blk >> 3) & 7;
  int b     = blk >> 6;
  int cloc  = t >> 5;                // 0..7 : this thread's conv channel
  int seg   = t & 31;                // 32 threads per channel
  int span  = seg * 8;               // 8 l-positions per thread per sub-tile
  int c     = gd * 8 + cloc;
  size_t rowbase = (size_t)(b * NC + gd * 8) * LL;
  const float* rowg = x + rowbase + (size_t)cloc * LL;   // this thread's channel row

  float wa[DWK], wm[DWK];
#pragma unroll
  for (int j = 0; j < DWK; ++j) {
    wa[j] = dwAw[c * DWK + j];
    wm[j] = dwMw[c * DWK + j];
  }
  float ba = dwAb[c], bm = dwMb[c];

  float sa = 0.f, qa = 0.f, sm = 0.f, qm = 0.f;
  int lbase = chunk * 4096;

  for (int st = 0; st < 16; ++st) {
    int l0s = lbase + st * 256;
    // stage 8 ch x 256 l (f32) -- coalesced, conflict-free
#pragma unroll
    for (int i = 0; i < 2; ++i) {
      int fid = i * 256 + t;         // 0..511 float4 slots
      int cr = fid >> 6, q = fid & 63;
      float4 v = *(const float4*)(x + rowbase + (size_t)cr * LL + l0s + q * 4);
      tile[cr][q * 4 + 0] = v.x; tile[cr][q * 4 + 1] = v.y;
      tile[cr][q * 4 + 2] = v.z; tile[cr][q * 4 + 3] = v.w;
    }
    __syncthreads();

    // conv stats: thread handles channel cloc, l in [span, span+8)
    float win[14];
#pragma unroll
    for (int jj = 0; jj < 14; ++jj) {
      int idx = span + jj - 3;
      if (idx >= 0 && idx < 256) {
        win[jj] = tile[cloc][idx];
      } else {
        int gl = l0s + idx;
        win[jj] = (gl >= 0 && gl < LL) ? rowg[gl] : 0.f;
      }
    }
#pragma unroll
    for (int u = 0; u < 8; ++u) {
      float ya = ba, ym = bm;
#pragma unroll
      for (int j = 0; j < DWK; ++j) {
        float xv = win[u + j];
        ya += wa[j] * xv;
        ym += wm[j] * xv;
      }
      sa += ya; qa += ya * ya;
      sm += ym; qm += ym * ym;
    }

    // xpose: thread t packs l = t, channels 0..7 -> one 16B store
    {
      uint4 pk;
      uint w0 = (uint)f2bf(tile[0][t]) | ((uint)f2bf(tile[1][t]) << 16);
      uint w1 = (uint)f2bf(tile[2][t]) | ((uint)f2bf(tile[3][t]) << 16);
      uint w2 = (uint)f2bf(tile[4][t]) | ((uint)f2bf(tile[5][t]) << 16);
      uint w3 = (uint)f2bf(tile[6][t]) | ((uint)f2bf(tile[7][t]) << 16);
      pk.x = w0; pk.y = w1; pk.z = w2; pk.w = w3;
      *(uint4*)(xT + ((size_t)(b * 8 + gd) * LL + l0s + t) * 8) = pk;
    }
    __syncthreads();   // before next stage overwrites tile
  }

  // reduce stats within each channel class (32 consecutive threads)
  red[t] = make_float4(sa, qa, sm, qm);
  __syncthreads();
#pragma unroll
  for (int s = 16; s > 0; s >>= 1) {
    if ((t & 31) < s) {
      float4 a = red[t], bb = red[t + s];
      red[t] = make_float4(a.x + bb.x, a.y + bb.y, a.z + bb.z, a.w + bb.w);
    }
    __syncthreads();
  }
  if ((t & 31) == 0) partial[(size_t)blk * 8 + cloc] = red[t];
}

// ---------------------------------------------------------------------------
// k_fin: fold 8 chunk-partials per (b,c) into {ga, ca, gm, cm}.
// ---------------------------------------------------------------------------
__global__ __launch_bounds__(256) void k_fin(
    const float4* __restrict__ partial,
    const float* __restrict__ gnAw, const float* __restrict__ gnAb,
    const float* __restrict__ gnMw, const float* __restrict__ gnMb,
    float4* __restrict__ stats4)
{
  int p = blockIdx.x * 256 + threadIdx.x;   // 0..511 = b*64 + cf
  if (p >= NB * NC) return;
  int b  = p >> 6;
  int cf = p & 63;
  int gd = cf >> 3, cl = cf & 7;
  float sa = 0.f, qa = 0.f, sm = 0.f, qm = 0.f;
#pragma unroll
  for (int ch = 0; ch < 8; ++ch) {
    float4 v = partial[(size_t)(((b * 8 + gd) * 8 + ch)) * 8 + cl];
    sa += v.x; qa += v.y; sm += v.z; qm += v.w;
  }
  float mua = sa / LL, vara = qa / LL - mua * mua;
  float mum = sm / LL, varm = qm / LL - mum * mum;
  float ga = gnAw[cf] * rsqrtf(vara + 1e-5f);
  float gm = gnMw[cf] * rsqrtf(varm + 1e-5f);
  stats4[p] = make_float4(ga, gnAb[cf] - mua * ga, gm, gnMb[cf] - mum * gm);
}

// ---------------------------------------------------------------------------
// k_mega: per (b, 256-l tile): stage xT tile (LDS, swizzled) -> inline
// dwconv+GN -> h tile (LDS) -> matvec40 (offs in regs / attn in LDS) ->
// deform gather + grouped conv -> out.  LDS: 32K xt + 32K ht = 64K.
// ---------------------------------------------------------------------------
__device__ __forceinline__ void unpack8(uint ux, uint uy, uint uz, uint uw,
                                        float* xv)
{
  xv[0] = bits2f(ux << 16); xv[1] = bits2f(ux & 0xffff0000u);
  xv[2] = bits2f(uy << 16); xv[3] = bits2f(uy & 0xffff0000u);
  xv[4] = bits2f(uz << 16); xv[5] = bits2f(uz & 0xffff0000u);
  xv[6] = bits2f(uw << 16); xv[7] = bits2f(uw & 0xffff0000u);
}

__device__ __forceinline__ void conv_gn(
    const ushort* __restrict__ xt, ushort* __restrict__ ht,
    const float* __restrict__ dww, const float* __restrict__ dwb,
    const float4* __restrict__ st4, int selM,
    const ushort* __restrict__ xTb, int l0, int t)
{
#pragma unroll
  for (int gd = 0; gd < 8; ++gd) {
    float w_[8][7];
    float acc[8];
#pragma unroll
    for (int i = 0; i < 8; ++i) {
      int c = gd * 8 + i;
      acc[i] = dwb[c];
#pragma unroll
      for (int j = 0; j < 7; ++j) w_[i][j] = dww[c * 7 + j];
    }
#pragma unroll
    for (int j = 0; j < 7; ++j) {
      int row = t + j - 3;
      float xv[8];
      if (row >= 0 && row < 256) {
        const ushort* pp = xt + row * 64 + ((gd ^ (row & 7)) << 3);
        uint2 a = *(const uint2*)pp;
        uint2 bb = *(const uint2*)(pp + 4);
        unpack8(a.x, a.y, bb.x, bb.y, xv);
      } else {
        int gl = l0 + row;
        if (gl >= 0 && gl < LL) {
          uint4 g = *(const uint4*)(xTb + ((size_t)gd * LL + gl) * 8);
          unpack8(g.x, g.y, g.z, g.w, xv);
        } else {
#pragma unroll
          for (int i = 0; i < 8; ++i) xv[i] = 0.f;
        }
      }
#pragma unroll
      for (int i = 0; i < 8; ++i) acc[i] += w_[i][j] * xv[i];
    }
#pragma unroll
    for (int i = 0; i < 8; ++i) {
      float4 s = st4[gd * 8 + i];
      float gg = selM ? s.z : s.x;
      float cc = selM ? s.w : s.y;
      ht[(gd * 8 + i) * 256 + t] = f2bf(acc[i] * gg + cc);
    }
  }
}

__device__ __forceinline__ void matvec40(
    const ushort* __restrict__ ht, const float* __restrict__ wt,
    const float* __restrict__ pb, int t, float* acc)
{
#pragma unroll
  for (int o = 0; o < NOFF; ++o) acc[o] = pb[o];
  for (int c = 0; c < NC; ++c) {
    float hv = bf2f(ht[c * 256 + t]);
    const float* wr = wt + c * NOFF;
#pragma unroll
    for (int o4 = 0; o4 < 10; ++o4) {
      float4 w = *(const float4*)(wr + (o4 << 2));
      acc[(o4 << 2) + 0] += w.x * hv;
      acc[(o4 << 2) + 1] += w.y * hv;
      acc[(o4 << 2) + 2] += w.z * hv;
      acc[(o4 << 2) + 3] += w.w * hv;
    }
  }
}

__global__ __launch_bounds__(256, 2) void k_mega(
    const ushort* __restrict__ xT,
    const float* __restrict__ wtA, const float* __restrict__ wtM,
    const float* __restrict__ pbA, const float* __restrict__ pbM,
    const float* __restrict__ dwAw, const float* __restrict__ dwAb,
    const float* __restrict__ dwMw, const float* __restrict__ dwMb,
    const float4* __restrict__ stats4,
    const float* __restrict__ wtW, const float* __restrict__ bias,
    float* __restrict__ out)
{
  __shared__ ushort s_xt[256 * 64];   // 32 KB (becomes attn store later)
  __shared__ ushort s_ht[64 * 256];   // 32 KB

  int t  = threadIdx.x;
  int b  = blockIdx.x >> 7;
  int l0 = (blockIdx.x & 127) << 8;
  const ushort* xTb = xT + (size_t)b * 8 * LL * 8;
  const float4* st4 = stats4 + b * 64;

  // ---- stage x tile (swizzled: cell(l,gd) at l*64 + ((gd^(l&7))*8)) ----
#pragma unroll
  for (int i = 0; i < 8; ++i) {
    int fid = i * 256 + t;
    int gd = fid >> 8, l = fid & 255;
    const uint2* src = (const uint2*)(xTb + ((size_t)gd * LL + l0 + l) * 8);
    ushort* dst = s_xt + l * 64 + ((gd ^ (l & 7)) << 3);
    uint2 a = src[0], bb = src[1];
    *(uint2*)dst = a;
    *(uint2*)(dst + 4) = bb;
  }
  __syncthreads();

  // ---- branch A: conv+GN -> ht, matvec -> offs(regs) ----
  conv_gn(s_xt, s_ht, dwAw, dwAb, st4, 0, xTb, l0, t);
  __syncthreads();

  float offs[NOFF];
  {
    float acc[NOFF];
    matvec40(s_ht, wtA, pbA, t, acc);
#pragma unroll
    for (int o = 0; o < NOFF; ++o) offs[o] = acc[o] * 4.f;
  }
  __syncthreads();   // everyone done reading ht(A)

  // ---- branch M: conv+GN -> ht (overwrite), matvec -> softmax -> LDS ----
  conv_gn(s_xt, s_ht, dwMw, dwMb, st4, 1, xTb, l0, t);
  __syncthreads();

  ushort* at_s = s_xt;   // x tile dead now; 20 KB of 32 KB reused
  {
    float acc[NOFF];
    matvec40(s_ht, wtM, pbM, t, acc);
#pragma unroll
    for (int g8 = 0; g8 < NGD; ++g8) {
      float mx = acc[g8 * 5];
#pragma unroll
      for (int j = 1; j < 5; ++j) mx = fmaxf(mx, acc[g8 * 5 + j]);
      float e[5]; float s = 0.f;
#pragma unroll
      for (int j = 0; j < 5; ++j) { e[j] = __expf(acc[g8 * 5 + j] - mx); s += e[j]; }
      float r = 1.f / s;
#pragma unroll
      for (int j = 0; j < 5; ++j)
        at_s[(g8 * 5 + j) * 256 + t] = f2bf(e[j] * r);
    }
  }
  // attn is self-read only (at_s[ch*256+t] written by thread t) -> no barrier

  // ---- deform ----
  int l = l0 + t;
#pragma unroll
  for (int g = 0; g < NG; ++g) {
    float acc16[16];
#pragma unroll
    for (int o = 0; o < 16; ++o) acc16[o] = 0.f;

#pragma unroll
    for (int d = 0; d < NDG; ++d) {
      const ushort* xr = xTb + (size_t)(g * 2 + d) * LL * 8;
#pragma unroll
      for (int k = 0; k < KK; ++k) {
        int ch = (g * 2 + d) * KK + k;
        float off = offs[ch];
        float at  = bf2f(at_s[ch * 256 + t]);
        float p   = (float)(l - 2 + k) + off;
        float p0f = floorf(p);
        float w1  = p - p0f;
        int p0 = (int)p0f;
        int p1 = p0 + 1;
        int i0 = min(max(p0, 0), LL - 1);
        int i1 = min(max(p1, 0), LL - 1);
        float f0 = (p0 >= 0 && p0 < LL) ? (1.f - w1) * at : 0.f;
        float f1 = (p1 >= 0 && p1 < LL) ? w1 * at : 0.f;
        uint4 u0 = *(const uint4*)(xr + (size_t)i0 * 8);
        uint4 u1 = *(const uint4*)(xr + (size_t)i1 * 8);
        float x0[8], x1[8];
        unpack8(u0.x, u0.y, u0.z, u0.w, x0);
        unpack8(u1.x, u1.y, u1.z, u1.w, x1);
#pragma unroll
        for (int c = 0; c < NCD; ++c) {
          float s = x0[c] * f0 + x1[c] * f1;
          const float* wpc = wtW + g * 1280 + ((d * 8 + c) * 5 + k) * 16;
#pragma unroll
          for (int o4 = 0; o4 < 4; ++o4) {
            float4 w = *(const float4*)(wpc + (o4 << 2));
            acc16[(o4 << 2) + 0] += w.x * s;
            acc16[(o4 << 2) + 1] += w.y * s;
            acc16[(o4 << 2) + 2] += w.z * s;
            acc16[(o4 << 2) + 3] += w.w * s;
          }
        }
      }
    }

    float* op = out + (size_t)(b * NC + g * 16) * LL + l;
#pragma unroll
    for (int o = 0; o < 16; ++o)
      op[(size_t)o * LL] = acc16[o] + bias[g * 16 + o];
  }
}

// ---------------------------------------------------------------------------
extern "C" void kernel_launch(void* const* d_in, const int* in_sizes, int n_in,
                              void* d_out, int out_size, void* d_ws, size_t ws_size,
                              hipStream_t stream)
{
  const float* x    = (const float*)d_in[0];
  const float* dwAw = (const float*)d_in[1];
  const float* dwAb = (const float*)d_in[2];
  const float* gnAw = (const float*)d_in[3];
  const float* gnAb = (const float*)d_in[4];
  const float* pwAw = (const float*)d_in[5];
  const float* pwAb = (const float*)d_in[6];
  const float* dwMw = (const float*)d_in[7];
  const float* dwMb = (const float*)d_in[8];
  const float* gnMw = (const float*)d_in[9];
  const float* gnMb = (const float*)d_in[10];
  const float* pwMw = (const float*)d_in[11];
  const float* pwMb = (const float*)d_in[12];
  const float* mw   = (const float*)d_in[13];
  const float* bias = (const float*)d_in[14];
  float* out = (float*)d_out;

  // ws: wt 40 KB | partial 64 KB | stats4 8 KB | xT 33.5 MB  (~33.7 MB)
  float* wtA = (float*)d_ws;                     // 2560 f32
  float* wtM = wtA + 2560;                       // 2560 f32
  float* wtW = wtM + 2560;                       // 5120 f32
  float4* partial = (float4*)(wtW + 5120);       // 512*8 float4
  float4* stats4  = partial + 4096;              // 512 float4
  ushort* xT = (ushort*)(stats4 + 512);          // 8*8*32768*8 ushort

  hipLaunchKernelGGL(k_prep, dim3(40), dim3(256), 0, stream,
                     pwAw, pwMw, mw, wtA, wtM, wtW);
  hipLaunchKernelGGL(k_statsx, dim3(512), dim3(256), 0, stream,
                     x, dwAw, dwAb, dwMw, dwMb, xT, partial);
  hipLaunchKernelGGL(k_fin, dim3(2), dim3(256), 0, stream,
                     partial, gnAw, gnAb, gnMw, gnMb, stats4);
  hipLaunchKernelGGL(k_mega, dim3(NB * (LL / 256)), dim3(256), 0, stream,
                     xT, wtA, wtM, pwAb, pwMb, dwAw, dwAb, dwMw, dwMb,
                     stats4, wtW, bias, out);
}

// Round 5
// 279.884 us; speedup vs baseline: 1.5625x; 1.5625x over previous
//
#include <hip/hip_runtime.h>
#include <hip/hip_bf16.h>

typedef unsigned int   uint;
typedef unsigned short ushort;

#define NB   8
#define NC   64
#define LL   32768
#define KK   5
#define NG   4
#define NDG  2
#define NGD  8        // NG*NDG
#define NCD  8        // NC / NGD
#define NOFF 40       // NGD*KK
#define DWK  7

__device__ __forceinline__ float bits2f(uint u) {
  union { uint u; float f; } v; v.u = u; return v.f;
}
__device__ __forceinline__ float bf2f(ushort u) {
  union { uint u; float f; } v; v.u = ((uint)u) << 16; return v.f;
}
__device__ __forceinline__ ushort f2bf(float f) {   // round-to-nearest-even
  union { float f; uint u; } v; v.f = f;
  uint r = (v.u + 0x7fffu + ((v.u >> 16) & 1u)) >> 16;
  return (ushort)r;
}
__device__ __forceinline__ void unpack8(uint ux, uint uy, uint uz, uint uw,
                                        float* xv)
{
  xv[0] = bits2f(ux << 16); xv[1] = bits2f(ux & 0xffff0000u);
  xv[2] = bits2f(uy << 16); xv[3] = bits2f(uy & 0xffff0000u);
  xv[4] = bits2f(uz << 16); xv[5] = bits2f(uz & 0xffff0000u);
  xv[6] = bits2f(uw << 16); xv[7] = bits2f(uw & 0xffff0000u);
}

// ---------------------------------------------------------------------------
// k_prep: permute f32 weights into MAC-friendly layouts.
//  wtA[c*40+o] = pw_off_w[o,c]   wtM[c*40+o] = pw_m_w[o,c]
//  wtW[(((g*2+d)*8+c)*5+k)*16+o] = weight[g*16+o, d*8+c, k]
// ---------------------------------------------------------------------------
__global__ __launch_bounds__(256) void k_prep(
    const float* __restrict__ pwA, const float* __restrict__ pwM,
    const float* __restrict__ mw,
    float* __restrict__ wtA, float* __restrict__ wtM, float* __restrict__ wtW)
{
  int idx = blockIdx.x * 256 + threadIdx.x;
  if (idx < 2560) {
    int c = idx / 40, o = idx % 40;
    wtA[idx] = pwA[o * NC + c];
  } else if (idx < 5120) {
    int j = idx - 2560;
    int c = j / 40, o = j % 40;
    wtM[j] = pwM[o * NC + c];
  } else if (idx < 10240) {
    int j = idx - 5120;
    int o = j & 15; int tt = j >> 4;
    int k = tt % 5;  tt /= 5;
    int c = tt % 8;  tt /= 8;
    int d = tt & 1;  int g = tt >> 1;
    wtW[j] = mw[((g * 16 + o) * 16 + d * 8 + c) * KK + k];
  }
}

// ---------------------------------------------------------------------------
// k_conv: ONE x pass. Depthwise conv7 for both branches -> raw y (bf16) +
// exact f32 row stats (sum, sumsq per branch). One block per (b,c) row.
// GN application is deferred (folded into pointwise weights by k_fin).
// ---------------------------------------------------------------------------
__device__ __forceinline__ void load8f(float* dst, const float* __restrict__ row,
                                       int start)
{
  if (start >= 0 && start + 8 <= LL) {
    float4 a = *(const float4*)(row + start);
    float4 b = *(const float4*)(row + start + 4);
    dst[0] = a.x; dst[1] = a.y; dst[2] = a.z; dst[3] = a.w;
    dst[4] = b.x; dst[5] = b.y; dst[6] = b.z; dst[7] = b.w;
  } else {
#pragma unroll
    for (int j = 0; j < 8; ++j) {
      int p = start + j;
      dst[j] = (p >= 0 && p < LL) ? row[p] : 0.f;
    }
  }
}

__global__ __launch_bounds__(256) void k_conv(
    const float* __restrict__ x,
    const float* __restrict__ dwAw, const float* __restrict__ dwAb,
    const float* __restrict__ dwMw, const float* __restrict__ dwMb,
    ushort* __restrict__ yA, ushort* __restrict__ yM,
    float4* __restrict__ partial)
{
  int tid = threadIdx.x;
  int bc  = blockIdx.x;           // b*64 + c
  int c   = bc & 63;
  const float* row = x + (size_t)bc * LL;

  float wa[DWK], wm[DWK];
#pragma unroll
  for (int j = 0; j < DWK; ++j) {
    wa[j] = dwAw[c * DWK + j];
    wm[j] = dwMw[c * DWK + j];
  }
  float ba = dwAb[c], bm = dwMb[c];

  ushort* oA = yA + (size_t)bc * LL;
  ushort* oM = yM + (size_t)bc * LL;

  float sa = 0.f, qa = 0.f, sm = 0.f, qm = 0.f;
  for (int it = 0; it < 16; ++it) {
    int m = it * 256 + tid;       // chunk index [0,4096)
    int lb = m * 8;
    float v[24];
    load8f(v + 0,  row, lb - 8);
    load8f(v + 8,  row, lb);
    load8f(v + 16, row, lb + 8);
    uint4 pA, pM;
    ushort* ppA = (ushort*)&pA;
    ushort* ppM = (ushort*)&pM;
#pragma unroll
    for (int u = 0; u < 8; ++u) {
      float ya = ba, ym = bm;
#pragma unroll
      for (int j = 0; j < DWK; ++j) {
        float xv = v[5 + u + j];  // x[lb+u-3+j]
        ya += wa[j] * xv;
        ym += wm[j] * xv;
      }
      sa += ya; qa += ya * ya;
      sm += ym; qm += ym * ym;
      ppA[u] = f2bf(ya);
      ppM[u] = f2bf(ym);
    }
    *(uint4*)(oA + lb) = pA;
    *(uint4*)(oM + lb) = pM;
  }

  __shared__ float4 red[256];
  red[tid] = make_float4(sa, qa, sm, qm);
  __syncthreads();
  for (int s = 128; s > 0; s >>= 1) {
    if (tid < s) {
      float4 a = red[tid], b = red[tid + s];
      red[tid] = make_float4(a.x + b.x, a.y + b.y, a.z + b.z, a.w + b.w);
    }
    __syncthreads();
  }
  if (tid == 0) partial[bc] = red[0];
}

// ---------------------------------------------------------------------------
// k_fin: per batch b, fold GN affine (and the x4 offset scale) into the
// pointwise weights/biases:  wAf[b,c,o] = 4*wtA[c,o]*gaA(b,c),
// bAf[b,o] = 4*(pbA[o] + sum_c wtA[c,o]*caA(b,c));  same for M (scale 1).
// Grid: 8 blocks (one per b) x 256 threads.
// ---------------------------------------------------------------------------
__global__ __launch_bounds__(256) void k_fin(
    const float4* __restrict__ partial,
    const float* __restrict__ gnAw, const float* __restrict__ gnAb,
    const float* __restrict__ gnMw, const float* __restrict__ gnMb,
    const float* __restrict__ wtA, const float* __restrict__ wtM,
    const float* __restrict__ pbA, const float* __restrict__ pbM,
    float* __restrict__ wAf, float* __restrict__ wMf,
    float* __restrict__ bAf, float* __restrict__ bMf)
{
  __shared__ float gA[64], cA[64], gM[64], cM[64];
  int b = blockIdx.x;
  int t = threadIdx.x;
  if (t < 64) {
    float4 v = partial[b * 64 + t];
    float mua = v.x / LL, vara = v.y / LL - mua * mua;
    float mum = v.z / LL, varm = v.w / LL - mum * mum;
    float ga = gnAw[t] * rsqrtf(vara + 1e-5f);
    float gm = gnMw[t] * rsqrtf(varm + 1e-5f);
    gA[t] = ga; cA[t] = gnAb[t] - mua * ga;
    gM[t] = gm; cM[t] = gnMb[t] - mum * gm;
  }
  __syncthreads();
  for (int idx = t; idx < 2560; idx += 256) {
    int c = idx / 40;
    wAf[b * 2560 + idx] = 4.f * wtA[idx] * gA[c];
    wMf[b * 2560 + idx] = wtM[idx] * gM[c];
  }
  if (t < 40) {
    float sA = 0.f, sM = 0.f;
    for (int c = 0; c < 64; ++c) {
      sA += wtA[c * 40 + t] * cA[c];
      sM += wtM[c * 40 + t] * cM[c];
    }
    bAf[b * 40 + t] = 4.f * (pbA[t] + sA);
    bMf[b * 40 + t] = pbM[t] + sM;
  }
}

// ---------------------------------------------------------------------------
// k_point: 40x64 matvec per position for both branches using per-b folded
// weights (GN pre-applied). Writes offs f32, attn bf16 (softmaxed).
// ---------------------------------------------------------------------------
__device__ __forceinline__ void stage_matvec40(
    const ushort* __restrict__ ysrc,   // y + b*64*LL + l0
    const float* __restrict__ wt,      // [c][40] folded f32
    const float* __restrict__ pb,      // folded bias [40]
    ushort* hs, int tid, float* acc)
{
#pragma unroll
  for (int i = 0; i < 8; ++i) {
    int fid = i * 256 + tid;
    int c = fid >> 5, q = fid & 31;
    ((uint4*)hs)[fid] = *(const uint4*)(ysrc + (size_t)c * LL + q * 8);
  }
  __syncthreads();
#pragma unroll
  for (int o = 0; o < NOFF; ++o) acc[o] = pb[o];
  for (int c = 0; c < NC; ++c) {
    float hv = bf2f(hs[(c << 8) + tid]);
    const float* wr = wt + c * NOFF;
#pragma unroll
    for (int o4 = 0; o4 < 10; ++o4) {
      float4 w = *(const float4*)(wr + (o4 << 2));
      acc[(o4 << 2) + 0] += w.x * hv;
      acc[(o4 << 2) + 1] += w.y * hv;
      acc[(o4 << 2) + 2] += w.z * hv;
      acc[(o4 << 2) + 3] += w.w * hv;
    }
  }
}

__global__ __launch_bounds__(256) void k_point(
    const ushort* __restrict__ yA, const ushort* __restrict__ yM,
    const float* __restrict__ wAf, const float* __restrict__ wMf,
    const float* __restrict__ bAf, const float* __restrict__ bMf,
    float* __restrict__ offs, ushort* __restrict__ attnB)
{
  __shared__ __align__(16) ushort hs[NC * 256];   // 32 KB
  int tid = threadIdx.x;
  int b   = blockIdx.x >> 7;
  int l0  = (blockIdx.x & 127) << 8;
  int l   = l0 + tid;
  float acc[NOFF];

  // ---- offset branch (x4 folded in) ----
  stage_matvec40(yA + (size_t)b * NC * LL + l0, wAf + b * 2560, bAf + b * 40,
                 hs, tid, acc);
  {
    float* op = offs + (size_t)b * NOFF * LL + l;
#pragma unroll
    for (int o = 0; o < NOFF; ++o) op[(size_t)o * LL] = acc[o];
  }
  __syncthreads();   // everyone done reading hs before restage

  // ---- mask branch + softmax ----
  stage_matvec40(yM + (size_t)b * NC * LL + l0, wMf + b * 2560, bMf + b * 40,
                 hs, tid, acc);
  {
    ushort* ap = attnB + (size_t)b * NOFF * LL + l;
#pragma unroll
    for (int g8 = 0; g8 < NGD; ++g8) {
      float mx = acc[g8 * 5];
#pragma unroll
      for (int j = 1; j < 5; ++j) mx = fmaxf(mx, acc[g8 * 5 + j]);
      float e[5]; float s = 0.f;
#pragma unroll
      for (int j = 0; j < 5; ++j) { e[j] = __expf(acc[g8 * 5 + j] - mx); s += e[j]; }
      float r = 1.f / s;
#pragma unroll
      for (int j = 0; j < 5; ++j)
        ap[(size_t)(g8 * 5 + j) * LL] = f2bf(e[j] * r);
    }
  }
}

// ---------------------------------------------------------------------------
// k_xpose: x (b,c,l) f32 -> xT (b, gd, l, 8) bf16: one tap gather = 16 B.
// ---------------------------------------------------------------------------
__global__ __launch_bounds__(256) void k_xpose(
    const float* __restrict__ x, ushort* __restrict__ xT)
{
  __shared__ __align__(16) float tile[8 * 256];
  int tid = threadIdx.x;
  int l0  = (blockIdx.x & 127) << 8;
  int gd  = (blockIdx.x >> 7) & 7;
  int b   = blockIdx.x >> 10;
  const float* src = x + (size_t)(b * NC + gd * 8) * LL + l0;
#pragma unroll
  for (int i = 0; i < 2; ++i) {
    int fid = i * 256 + tid;          // 512 float4 = 8 rows x 64 float4
    int c = fid >> 6, q = fid & 63;
    *(float4*)(tile + c * 256 + q * 4) =
        *(const float4*)(src + (size_t)c * LL + q * 4);
  }
  __syncthreads();
  uint4 pk;
  pk.x = (uint)f2bf(tile[0 * 256 + tid]) | ((uint)f2bf(tile[1 * 256 + tid]) << 16);
  pk.y = (uint)f2bf(tile[2 * 256 + tid]) | ((uint)f2bf(tile[3 * 256 + tid]) << 16);
  pk.z = (uint)f2bf(tile[4 * 256 + tid]) | ((uint)f2bf(tile[5 * 256 + tid]) << 16);
  pk.w = (uint)f2bf(tile[6 * 256 + tid]) | ((uint)f2bf(tile[7 * 256 + tid]) << 16);
  *(uint4*)(xT + ((size_t)(b * 8 + gd) * LL + l0 + tid) * 8) = pk;
}

// ---------------------------------------------------------------------------
// k_deform: gather (16B bf16) + lerp + attn + grouped conv accumulate.
// One block = (b, g, 256 l); thread owns all 16 out channels of g.
// ---------------------------------------------------------------------------
__global__ __launch_bounds__(256) void k_deform(
    const ushort* __restrict__ xT, const float* __restrict__ offs,
    const ushort* __restrict__ attnB, const float* __restrict__ wtW,
    const float* __restrict__ bias, float* __restrict__ out)
{
  int tid  = threadIdx.x;
  int lblk = blockIdx.x & 127;
  int g    = (blockIdx.x >> 7) & 3;
  int b    = blockIdx.x >> 9;
  int l    = (lblk << 8) + tid;

  float acc16[16];
#pragma unroll
  for (int o = 0; o < 16; ++o) acc16[o] = 0.f;

  const float*  offp = offs  + (size_t)b * NOFF * LL + l;
  const ushort* attp = attnB + (size_t)b * NOFF * LL + l;

#pragma unroll
  for (int d = 0; d < NDG; ++d) {
    const ushort* xr = xT + (size_t)(b * 8 + g * 2 + d) * LL * 8;
#pragma unroll
    for (int k = 0; k < KK; ++k) {
      int ch = (g * 2 + d) * KK + k;
      float off = offp[(size_t)ch * LL];
      float at  = bf2f(attp[(size_t)ch * LL]);
      float p   = (float)(l - 2 + k) + off;
      float p0f = floorf(p);
      float w1  = p - p0f;
      int p0 = (int)p0f;
      int p1 = p0 + 1;
      int i0 = min(max(p0, 0), LL - 1);
      int i1 = min(max(p1, 0), LL - 1);
      float f0 = (p0 >= 0 && p0 < LL) ? (1.f - w1) * at : 0.f;
      float f1 = (p1 >= 0 && p1 < LL) ? w1 * at : 0.f;
      uint4 u0 = *(const uint4*)(xr + (size_t)i0 * 8);
      uint4 u1 = *(const uint4*)(xr + (size_t)i1 * 8);
      float x0[8], x1[8];
      unpack8(u0.x, u0.y, u0.z, u0.w, x0);
      unpack8(u1.x, u1.y, u1.z, u1.w, x1);
#pragma unroll
      for (int c = 0; c < NCD; ++c) {
        float s = x0[c] * f0 + x1[c] * f1;
        const float* wpc = wtW + g * 1280 + ((d * 8 + c) * 5 + k) * 16;
#pragma unroll
        for (int o4 = 0; o4 < 4; ++o4) {
          float4 w = *(const float4*)(wpc + (o4 << 2));
          acc16[(o4 << 2) + 0] += w.x * s;
          acc16[(o4 << 2) + 1] += w.y * s;
          acc16[(o4 << 2) + 2] += w.z * s;
          acc16[(o4 << 2) + 3] += w.w * s;
        }
      }
    }
  }

  float* op = out + (size_t)(b * NC + g * 16) * LL + l;
#pragma unroll
  for (int o = 0; o < 16; ++o)
    op[(size_t)o * LL] = acc16[o] + bias[g * 16 + o];
}

// ---------------------------------------------------------------------------
extern "C" void kernel_launch(void* const* d_in, const int* in_sizes, int n_in,
                              void* d_out, int out_size, void* d_ws, size_t ws_size,
                              hipStream_t stream)
{
  const float* x    = (const float*)d_in[0];
  const float* dwAw = (const float*)d_in[1];
  const float* dwAb = (const float*)d_in[2];
  const float* gnAw = (const float*)d_in[3];
  const float* gnAb = (const float*)d_in[4];
  const float* pwAw = (const float*)d_in[5];
  const float* pwAb = (const float*)d_in[6];
  const float* dwMw = (const float*)d_in[7];
  const float* dwMb = (const float*)d_in[8];
  const float* gnMw = (const float*)d_in[9];
  const float* gnMb = (const float*)d_in[10];
  const float* pwMw = (const float*)d_in[11];
  const float* pwMb = (const float*)d_in[12];
  const float* mw   = (const float*)d_in[13];
  const float* bias = (const float*)d_in[14];
  float* out = (float*)d_out;

  // ws layout (~130.5 MB peak):
  //  wt/wf/bias/partial ~0.22 MB | yA 33.5 | yM 33.5 | offs 41.9 | attn 21
  //  xT (33.5) aliases yA after k_point (k_xpose runs after k_point).
  float* wtA = (float*)d_ws;                     // 2560
  float* wtM = wtA + 2560;                       // 2560
  float* wtW = wtM + 2560;                       // 5120
  float* wAf = wtW + 5120;                       // 8*2560
  float* wMf = wAf + 20480;                      // 8*2560
  float* bAf = wMf + 20480;                      // 8*40
  float* bMf = bAf + 320;                        // 8*40
  float4* partial = (float4*)(bMf + 320);        // 512 float4
  ushort* yA = (ushort*)(partial + 512);         // 16.78M ushort
  ushort* yM = yA + (size_t)NB * NC * LL;        // 16.78M ushort
  float* offs = (float*)(yM + (size_t)NB * NC * LL);   // 10.49M f32
  ushort* attnB = (ushort*)(offs + (size_t)NB * NOFF * LL); // 10.49M ushort
  ushort* xT = yA;   // y dead after k_point

  hipLaunchKernelGGL(k_prep, dim3(40), dim3(256), 0, stream,
                     pwAw, pwMw, mw, wtA, wtM, wtW);
  hipLaunchKernelGGL(k_conv, dim3(NB * NC), dim3(256), 0, stream,
                     x, dwAw, dwAb, dwMw, dwMb, yA, yM, partial);
  hipLaunchKernelGGL(k_fin, dim3(NB), dim3(256), 0, stream,
                     partial, gnAw, gnAb, gnMw, gnMb, wtA, wtM, pwAb, pwMb,
                     wAf, wMf, bAf, bMf);
  hipLaunchKernelGGL(k_point, dim3(NB * (LL / 256)), dim3(256), 0, stream,
                     yA, yM, wAf, wMf, bAf, bMf, offs, attnB);
  hipLaunchKernelGGL(k_xpose, dim3(NB * NGD * (LL / 256)), dim3(256), 0, stream,
                     x, xT);
  hipLaunchKernelGGL(k_deform, dim3(NB * NG * (LL / 256)), dim3(256), 0, stream,
                     xT, offs, attnB, wtW, bias, out);
}